// Round 2
// baseline (232.015 us; speedup 1.0000x reference)
//
#include <hip/hip_runtime.h>

#define IN_CH 64
#define HID   16
#define OUTC  8

// Workspace budget is tight: total ws use = 33*N floats (~6.3 MB).
//   [0, 16N)    s1   : layer-1 aggregated (projected) messages, zeroed
//   [16N, 17N)  deg  : in-degree, zeroed
//   [17N, 33N)  A    : phase 1 = y1 (16N); after scatter1: y2 = A[0,8N),
//                      s2 = A[8N,16N) (zeroed by 2nd memset)
// r1 is recomputed in node_xform2 (re-reads x); r2 lives in d_out.

// ---------------------------------------------------------------------------
// Layer-1 projection: y1 = x @ W1l^T.
// 256 threads = 16 nodes x 16 output channels. W1l in LDS transposed [k][c].
// ---------------------------------------------------------------------------
__global__ __launch_bounds__(256) void node_xform1(
    const float* __restrict__ x,
    const float* __restrict__ W1l,
    float* __restrict__ y1,
    int n_nodes)
{
    __shared__ float sWl[IN_CH * HID];  // [k][c]: k*16 + c
    int tid = threadIdx.x;
    for (int i = tid; i < IN_CH * HID; i += 256) {
        int c = i >> 6;      // W1l is [HID][IN_CH]
        int k = i & 63;
        sWl[k * HID + c] = W1l[i];
    }
    __syncthreads();

    int node = blockIdx.x * 16 + (tid >> 4);
    int c    = tid & 15;
    if (node >= n_nodes) return;

    const float* xr = x + (size_t)node * IN_CH;
    float acc = 0.f;
#pragma unroll
    for (int k = 0; k < IN_CH; k += 4) {
        float4 xv = *(const float4*)(xr + k);
        acc = fmaf(xv.x, sWl[(k + 0) * HID + c], acc);
        acc = fmaf(xv.y, sWl[(k + 1) * HID + c], acc);
        acc = fmaf(xv.z, sWl[(k + 2) * HID + c], acc);
        acc = fmaf(xv.w, sWl[(k + 3) * HID + c], acc);
    }
    y1[node * HID + c] = acc;
}

// ---------------------------------------------------------------------------
// Layer-1 scatter: s1[dst] += y1[src] (16 ch), deg[dst] += 1
// ---------------------------------------------------------------------------
__global__ __launch_bounds__(256) void scatter1(
    const float* __restrict__ y1,
    const int*   __restrict__ esrc,
    const int*   __restrict__ edst,
    float* __restrict__ s1,
    float* __restrict__ deg,
    int n_edges)
{
    int gid = blockIdx.x * 256 + threadIdx.x;
    int e = gid >> 4;
    if (e >= n_edges) return;
    int c = gid & 15;
    int s = esrc[e];
    int d = edst[e];
    atomicAdd(&s1[d * HID + c], y1[s * HID + c]);
    if (c == 0) atomicAdd(&deg[d], 1.0f);
}

// ---------------------------------------------------------------------------
// Layer-2 node transform. Per node:
//   r1  = x @ W1r^T + b1            (recomputed, saves 16N ws floats)
//   h   = relu(s1/max(deg,1) + r1)  (staged in LDS)
//   y2  = h @ W2l^T                 -> ws (A[0,8N))
//   r2  = h @ W2r^T + b2            -> d_out
// 16 threads/node: phase A each thread computes one h channel; phase B
// threads 0..7 compute y2 channels, threads 8..15 compute r2 channels.
// ---------------------------------------------------------------------------
__global__ __launch_bounds__(256) void node_xform2(
    const float* __restrict__ x,
    const float* __restrict__ s1,
    const float* __restrict__ deg,
    const float* __restrict__ W1r,
    const float* __restrict__ b1,
    const float* __restrict__ W2l,
    const float* __restrict__ W2r,
    const float* __restrict__ b2,
    float* __restrict__ y2,
    float* __restrict__ r2out,
    int n_nodes)
{
    __shared__ float sW1r[IN_CH * HID];   // [k][c]: k*16 + c
    __shared__ float sW2l[HID * OUTC];    // [k][c]: k*8 + c
    __shared__ float sW2r[HID * OUTC];
    __shared__ float sb1[HID];
    __shared__ float sb2[OUTC];
    __shared__ float sh[16 * HID];        // h values for the block's 16 nodes

    int tid = threadIdx.x;
    for (int i = tid; i < IN_CH * HID; i += 256) {
        int c = i >> 6;
        int k = i & 63;
        sW1r[k * HID + c] = W1r[i];
    }
    for (int i = tid; i < HID * OUTC; i += 256) {
        int c = i >> 4;   // W2 is [OUTC][HID]
        int k = i & 15;
        sW2l[k * OUTC + c] = W2l[i];
        sW2r[k * OUTC + c] = W2r[i];
    }
    if (tid < HID)  sb1[tid] = b1[tid];
    if (tid < OUTC) sb2[tid] = b2[tid];
    __syncthreads();

    int ln   = tid >> 4;             // local node 0..15
    int t    = tid & 15;
    int node = blockIdx.x * 16 + ln;
    bool ok  = node < n_nodes;

    if (ok) {
        float inv = 1.0f / fmaxf(deg[node], 1.0f);
        const float* xr = x + (size_t)node * IN_CH;
        float acc = 0.f;
#pragma unroll
        for (int k = 0; k < IN_CH; k += 4) {
            float4 xv = *(const float4*)(xr + k);
            acc = fmaf(xv.x, sW1r[(k + 0) * HID + t], acc);
            acc = fmaf(xv.y, sW1r[(k + 1) * HID + t], acc);
            acc = fmaf(xv.z, sW1r[(k + 2) * HID + t], acc);
            acc = fmaf(xv.w, sW1r[(k + 3) * HID + t], acc);
        }
        float hv = fmaxf(fmaf(s1[node * HID + t], inv, acc + sb1[t]), 0.0f);
        sh[ln * HID + t] = hv;
    }
    __syncthreads();
    if (!ok) return;

    if (t < OUTC) {
        float acc = 0.f;
#pragma unroll
        for (int k = 0; k < HID; ++k)
            acc = fmaf(sh[ln * HID + k], sW2l[k * OUTC + t], acc);
        y2[node * OUTC + t] = acc;
    } else {
        int c = t - OUTC;
        float acc = sb2[c];
#pragma unroll
        for (int k = 0; k < HID; ++k)
            acc = fmaf(sh[ln * HID + k], sW2r[k * OUTC + c], acc);
        r2out[node * OUTC + c] = acc;
    }
}

// ---------------------------------------------------------------------------
// Layer-2 scatter: s2[dst] += y2[src] (8 ch)
// ---------------------------------------------------------------------------
__global__ __launch_bounds__(256) void scatter2(
    const float* __restrict__ y2,
    const int*   __restrict__ esrc,
    const int*   __restrict__ edst,
    float* __restrict__ s2,
    int n_edges)
{
    int gid = blockIdx.x * 256 + threadIdx.x;
    int e = gid >> 3;
    if (e >= n_edges) return;
    int c = gid & 7;
    int s = esrc[e];
    int d = edst[e];
    atomicAdd(&s2[d * OUTC + c], y2[s * OUTC + c]);
}

// ---------------------------------------------------------------------------
// Epilogue: out = s2/max(deg,1) + out   (out already holds r2)
// ---------------------------------------------------------------------------
__global__ __launch_bounds__(256) void epilogue(
    const float* __restrict__ s2,
    const float* __restrict__ deg,
    float* __restrict__ out,
    int n_elems)
{
    int i = blockIdx.x * 256 + threadIdx.x;
    if (i >= n_elems) return;
    float dv = fmaxf(deg[i >> 3], 1.0f);
    out[i] = s2[i] / dv + out[i];
}

extern "C" void kernel_launch(void* const* d_in, const int* in_sizes, int n_in,
                              void* d_out, int out_size, void* d_ws, size_t ws_size,
                              hipStream_t stream)
{
    const float* x   = (const float*)d_in[0];
    const float* W1l = (const float*)d_in[1];
    const float* W1r = (const float*)d_in[2];
    const float* b1  = (const float*)d_in[3];
    const float* W2l = (const float*)d_in[4];
    const float* W2r = (const float*)d_in[5];
    const float* b2  = (const float*)d_in[6];
    const int*   ei  = (const int*)d_in[7];

    int n_nodes = in_sizes[0] / IN_CH;       // 50000
    int n_edges = in_sizes[7] / 2;           // 800000
    const int* esrc = ei;
    const int* edst = ei + n_edges;

    float* out = (float*)d_out;

    // ws layout: s1 (16N) | deg (N) | A (16N)  -> 33N floats total (~6.3 MB)
    float* ws  = (float*)d_ws;
    float* s1  = ws;
    float* deg = s1 + (size_t)n_nodes * HID;
    float* A   = deg + n_nodes;
    float* y1  = A;                               // phase 1
    float* y2  = A;                               // phase 2 (first 8N)
    float* s2  = A + (size_t)n_nodes * OUTC;      // phase 2 (second 8N)

    dim3 blk(256);

    // zero s1 + deg (contiguous 17N floats)
    hipMemsetAsync(s1, 0, (size_t)n_nodes * (HID + 1) * sizeof(float), stream);

    node_xform1<<<dim3((n_nodes + 15) / 16), blk, 0, stream>>>(
        x, W1l, y1, n_nodes);

    scatter1<<<dim3(((size_t)n_edges * HID + 255) / 256), blk, 0, stream>>>(
        y1, esrc, edst, s1, deg, n_edges);

    // y1 dead now; zero the s2 half of A
    hipMemsetAsync(s2, 0, (size_t)n_nodes * OUTC * sizeof(float), stream);

    node_xform2<<<dim3((n_nodes + 15) / 16), blk, 0, stream>>>(
        x, s1, deg, W1r, b1, W2l, W2r, b2, y2, out, n_nodes);

    scatter2<<<dim3(((size_t)n_edges * OUTC + 255) / 256), blk, 0, stream>>>(
        y2, esrc, edst, s2, n_edges);

    int n_out = n_nodes * OUTC;
    epilogue<<<dim3((n_out + 255) / 256), blk, 0, stream>>>(
        s2, deg, out, n_out);
}